// Round 5
// baseline (389.631 us; speedup 1.0000x reference)
//
#include <hip/hip_runtime.h>
#include <hip/hip_bf16.h>
#include <cstdint>

// SNN: Poisson encode (noise < x) -> [T=32] { h = sp@W1^T; v+=h; spike=(v>1); v-=spike; logits += spike@W2^T }
// B=8192, T=32, D_IN=784 (pad K to 800 = 25x32), D_H=100 (pad N to 128), D_OUT=10.
//
// v5: cheap bit->bf16 expansion via permuted bit storage.
//  Stored bit position p for k-elem i (within a 32-block): p = (i>>1) + 16*(i&1).
//  Then dword d of lane's A-fragment = ((g >> ((lane>>4)*4 + d)) & 0x10001) * 0x3F80
//  -- 3 VALU per dword (was ~7). bit_gemm goes VALU-bound -> MFMA-bound.
//
//  K0 prep_w1   : W1 -> MFMA-B-fragment bf16 hi/lo pairs in ws (exact f32 = hi+lo).
//  K1 spike_pack: stream noise+x once, ballot-pack permuted spike bits.
//  K2 bit_gemm  : H[t,b,h] via mfma_f32_16x16x32_bf16; no LDS, no barriers.
//  K3 snn_scan  : IF scan over t, logits = spikecount @ W2^T.

typedef __attribute__((ext_vector_type(8))) short bf16x8;
typedef __attribute__((ext_vector_type(4))) float f32x4;

#define D_IN 784
#define NB 8192
#define KT 25   // K tiles of 32 (800 padded)
#define NTL 8   // N tiles of 16 (128 padded)
#define DH 100

// ---------------- K0: pack W1 into fragment-ready bf16 hi/lo ----------------
// Fragment f = (kt*8 + nt), stored as [f][hi(512 ushorts) | lo(512 ushorts)].
// B-slot(lane l, elem j): n = nt*16 + (l&15), i = kt*32 + (l>>4)*8 + j.
__global__ void prep_w1(const float* __restrict__ W1, unsigned short* __restrict__ wf) {
    int idx = blockIdx.x * 256 + threadIdx.x;           // 25*8*64 = 12800
    if (idx >= KT * NTL * 64) return;
    int l  = idx & 63;
    int nt = (idx >> 6) & 7;
    int kt = idx >> 9;
    int n  = nt * 16 + (l & 15);
    int i0 = kt * 32 + (l >> 4) * 8;
    size_t fbase = (size_t)(kt * 8 + nt) * 1024;
    #pragma unroll
    for (int j = 0; j < 8; ++j) {
        int i = i0 + j;
        float w = (n < DH && i < D_IN) ? W1[n * D_IN + i] : 0.f;
        uint32_t ub = __float_as_uint(w);
        uint32_t rh = ub + 0x7FFFu + ((ub >> 16) & 1u);
        unsigned short h = (unsigned short)(rh >> 16);
        float hf = __uint_as_float(((uint32_t)h) << 16);
        float resid = w - hf;
        uint32_t ul = __float_as_uint(resid);
        uint32_t rl = ul + 0x7FFFu + ((ul >> 16) & 1u);
        unsigned short lo = (unsigned short)(rl >> 16);
        wf[fbase + l * 8 + j]       = h;
        wf[fbase + 512 + l * 8 + j] = lo;
    }
}

// ---------------- K1: spike bitpack (permuted bit order) ----------------
// Wave w: b-pair {2*(w/25), +1} x kt = w%25. Lane: b = bp*2 + (lane>>5),
// q = lane&31 holds i = kt*32 + ((q&15)<<1 | (q>>4))  [so stored bit position
// q corresponds to p(i) = (i>>1) + 16*(i&1)]. Same 128B line coverage as linear.
__global__ __launch_bounds__(256) void spike_pack(const float* __restrict__ x,
                                                  const float* __restrict__ noise,
                                                  uint32_t* __restrict__ bits) {
    const int tid  = threadIdx.x;
    const int lane = tid & 63;
    const int w    = blockIdx.x * 4 + (tid >> 6);       // 0 .. 102399
    const int kt   = w % 25;
    const int bp   = w / 25;
    const int b    = bp * 2 + (lane >> 5);
    const int q    = lane & 31;
    const int i    = kt * 32 + (((q & 15) << 1) | (q >> 4));
    const int ic   = i < D_IN ? i : D_IN - 1;
    const bool valid = (i < D_IN);
    const size_t ro = (size_t)b * D_IN + ic;
    const float xv  = x[ro];
    float nv[32];
    #pragma unroll
    for (int t = 0; t < 32; ++t)
        nv[t] = noise[(size_t)t * ((size_t)NB * D_IN) + ro];
    #pragma unroll
    for (int t = 0; t < 32; ++t) {
        unsigned long long m = __ballot(valid && (nv[t] < xv));
        if ((lane & 31) == 0)
            bits[(size_t)(t * KT + kt) * NB + b] = (uint32_t)(m >> lane);
    }
}

// ---------------- K2: H = spikes @ W1^T, bits input, no LDS/barriers ----------------
// Block: 256 thr = 4 waves as 2(M)x2(N); tile 128 rows x 128 h; grid 2048 = 32t x 64 btiles.
// A-fragment dword d: bits {even,odd} at stored positions {a, a+16}, a = (lane>>4)*4+d:
//   pk.u[d] = ((g >> a) & 0x10001) * 0x3F80
__global__ __launch_bounds__(256) void bit_gemm(const uint32_t* __restrict__ bits,
                                                const unsigned short* __restrict__ wf,
                                                float* __restrict__ H) {
    const int tid   = threadIdx.x;
    const int lane  = tid & 63;
    const int wave  = tid >> 6;
    const int Mhalf = wave >> 1;
    const int Nhalf = wave & 1;
    const int bid   = blockIdx.x;
    const int btile = bid & 63;
    const int t     = bid >> 6;
    const int b0    = btile * 128;
    const int rowBase = b0 + Mhalf * 64 + (lane & 15);
    const int a0      = (lane >> 4) * 4;

    f32x4 acc[4][4];
    #pragma unroll
    for (int i = 0; i < 4; ++i)
        #pragma unroll
        for (int j = 0; j < 4; ++j) acc[i][j] = (f32x4){0.f, 0.f, 0.f, 0.f};

    #pragma unroll 2
    for (int kt = 0; kt < KT; ++kt) {
        const uint32_t* bptr = bits + (size_t)(t * KT + kt) * NB;
        uint32_t g[4];
        #pragma unroll
        for (int mt = 0; mt < 4; ++mt) g[mt] = bptr[rowBase + mt * 16];

        bf16x8 afr[4];
        #pragma unroll
        for (int mt = 0; mt < 4; ++mt) {
            union { uint32_t u[4]; bf16x8 v; } pk;
            #pragma unroll
            for (int d = 0; d < 4; ++d)
                pk.u[d] = ((g[mt] >> (a0 + d)) & 0x10001u) * 0x3F80u;
            afr[mt] = pk.v;
        }
        #pragma unroll
        for (int nt = 0; nt < 4; ++nt) {
            const size_t fo = (size_t)(kt * 8 + Nhalf * 4 + nt) * 1024 + lane * 8;
            const bf16x8 bhi = *reinterpret_cast<const bf16x8*>(wf + fo);
            const bf16x8 blo = *reinterpret_cast<const bf16x8*>(wf + fo + 512);
            #pragma unroll
            for (int mt = 0; mt < 4; ++mt) {
                acc[mt][nt] = __builtin_amdgcn_mfma_f32_16x16x32_bf16(afr[mt], bhi, acc[mt][nt], 0, 0, 0);
                acc[mt][nt] = __builtin_amdgcn_mfma_f32_16x16x32_bf16(afr[mt], blo, acc[mt][nt], 0, 0, 0);
            }
        }
    }
    // C/D layout: col = lane&15, row = (lane>>4)*4 + reg.  H compact [.,100].
    const int colBase   = Nhalf * 64 + (lane & 15);
    const int rowInTile = (lane >> 4) * 4;
    #pragma unroll
    for (int mt = 0; mt < 4; ++mt) {
        const size_t rg = (size_t)t * NB + b0 + Mhalf * 64 + mt * 16 + rowInTile;
        #pragma unroll
        for (int nt = 0; nt < 4; ++nt) {
            const int col = colBase + nt * 16;
            if (col < DH) {
                #pragma unroll
                for (int r = 0; r < 4; ++r)
                    H[(rg + r) * DH + col] = acc[mt][nt][r];
            }
        }
    }
}

// ---------------- K3: IF scan over t + logits = cnt @ W2^T ----------------
__global__ __launch_bounds__(256) void snn_scan(const float* __restrict__ H,
                                                const float* __restrict__ W2,
                                                float* __restrict__ out) {
    __shared__ float cbuf[2][104];
    __shared__ float w2s[1000];
    const int tid = threadIdx.x;
    const int r = tid >> 7, h = tid & 127;
    const size_t b = (size_t)blockIdx.x * 2 + r;
    for (int i = tid; i < 1000; i += 256) w2s[i] = W2[i];

    float cnt = 0.f;
    if (h < DH) {
        float hv[32];
        #pragma unroll
        for (int t = 0; t < 32; ++t) hv[t] = H[((size_t)t * NB + b) * DH + h];
        float v = 0.f;
        #pragma unroll
        for (int t = 0; t < 32; ++t) {
            v += hv[t];
            float s = (v - 1.0f > 0.0f) ? 1.0f : 0.0f;  // exact reference semantics
            v -= s;
            cnt += s;
        }
    }
    if (h < DH) cbuf[r][h] = cnt;
    __syncthreads();
    if (tid < 20) {
        const int rr = tid / 10, o = tid % 10;
        float s = 0.f;
        for (int hh = 0; hh < DH; ++hh) s += cbuf[rr][hh] * w2s[o * DH + hh];
        out[((size_t)blockIdx.x * 2 + rr) * 10 + o] = s;
    }
}

extern "C" void kernel_launch(void* const* d_in, const int* in_sizes, int n_in,
                              void* d_out, int out_size, void* d_ws, size_t ws_size,
                              hipStream_t stream) {
    const float* x     = (const float*)d_in[0];   // [8192,784]
    const float* noise = (const float*)d_in[1];   // [32,8192,784]
    const float* W1    = (const float*)d_in[2];   // [100,784]
    const float* W2    = (const float*)d_in[3];   // [10,100]
    float* out = (float*)d_out;                   // [8192,10]

    unsigned short* wf = (unsigned short*)d_ws;                      // 400 KB W1 frags
    uint32_t* bits = (uint32_t*)((char*)d_ws + (1u << 20));          // 26.2 MB spike bits
    float* H = (float*)((char*)d_ws + (32u << 20));                  // 104.9 MB H buffer

    prep_w1<<<50, 256, 0, stream>>>(W1, wf);
    spike_pack<<<25600, 256, 0, stream>>>(x, noise, bits);
    bit_gemm<<<2048, 256, 0, stream>>>(bits, wf, H);
    snn_scan<<<4096, 256, 0, stream>>>(H, W2, out);
}

// Round 6
// 364.202 us; speedup vs baseline: 1.0698x; 1.0698x over previous
//
#include <hip/hip_runtime.h>
#include <hip/hip_bf16.h>
#include <cstdint>

// SNN: Poisson encode (noise < x) -> [T=32] { h = sp@W1^T; v+=h; spike=(v>1); v-=spike; logits += spike@W2^T }
// B=8192, T=32, D_IN=784 (pad K to 800 = 25x32), D_H=100 (pad N to 128), D_OUT=10.
//
// v6: fully-contiguous noise streaming.
//  K0 prep_w1    : W1 -> MFMA-B-fragment bf16 hi/lo pairs in ws (exact f32 = hi+lo).
//  K1 pack_contig: block = (t, 128-row panel). Lane-linear float4 reads of noise+x
//                  (1KB/wave-instr), ballot-pack bits -> LDS [128][50] ushorts,
//                  cooperative transposed write -> bits[(t*25+kt)*8192+b] dwords.
//                  Stored bit q within ushort <-> float offset f: q = 4*(f&3)+(f>>2).
//  K2 bit_gemm   : H[b][t][100] via mfma_f32_16x16x32_bf16; no LDS/barriers.
//  K3 snn_scan   : IF scan over t (contiguous H rows), logits = cnt @ W2^T.

typedef __attribute__((ext_vector_type(8))) short bf16x8;
typedef __attribute__((ext_vector_type(4))) float f32x4;

#define D_IN 784
#define NB 8192
#define KT 25   // K tiles of 32 (800 padded)
#define NTL 8   // N tiles of 16 (128 padded)
#define DH 100

// ---------------- K0: pack W1 into fragment-ready bf16 hi/lo ----------------
// Fragment f = (kt*8 + nt), stored as [f][hi(512 ushorts) | lo(512 ushorts)].
// B-slot(lane l, elem j): n = nt*16 + (l&15), i = kt*32 + (l>>4)*8 + j.
__global__ void prep_w1(const float* __restrict__ W1, unsigned short* __restrict__ wf) {
    int idx = blockIdx.x * 256 + threadIdx.x;           // 25*8*64 = 12800
    if (idx >= KT * NTL * 64) return;
    int l  = idx & 63;
    int nt = (idx >> 6) & 7;
    int kt = idx >> 9;
    int n  = nt * 16 + (l & 15);
    int i0 = kt * 32 + (l >> 4) * 8;
    size_t fbase = (size_t)(kt * 8 + nt) * 1024;
    #pragma unroll
    for (int j = 0; j < 8; ++j) {
        int i = i0 + j;
        float w = (n < DH && i < D_IN) ? W1[n * D_IN + i] : 0.f;
        uint32_t ub = __float_as_uint(w);
        uint32_t rh = ub + 0x7FFFu + ((ub >> 16) & 1u);
        unsigned short h = (unsigned short)(rh >> 16);
        float hf = __uint_as_float(((uint32_t)h) << 16);
        float resid = w - hf;
        uint32_t ul = __float_as_uint(resid);
        uint32_t rl = ul + 0x7FFFu + ((ul >> 16) & 1u);
        unsigned short lo = (unsigned short)(rl >> 16);
        wf[fbase + l * 8 + j]       = h;
        wf[fbase + 512 + l * 8 + j] = lo;
    }
}

// ---------------- K1: contiguous spike bitpack ----------------
// Block (t, btile): rows b0..b0+127, 128*784 floats = 25088 float4 = 98 passes x 256 thr.
// Wave covers 256 consecutive floats/pass = 16 ushort-groups (784 = 49*16, groups never
// straddle rows). ballot_j bit l = spike(float4 l, comp j); ushort u (lane<16):
// v = sum_j bfe(ballot_j, 4u, 4) << 4j  ->  bit q = 4*jj + lambda, float = 16g + 4*lambda + jj.
// LDS sB[128][50]; col 49 = pad (zeroed). Out: dword (b,kt) = ushorts [b][2kt..2kt+1].
__global__ __launch_bounds__(256) void pack_contig(const float* __restrict__ x,
                                                   const float* __restrict__ noise,
                                                   uint32_t* __restrict__ bits) {
    __shared__ __align__(4) unsigned short sB[128 * 50];   // 12.8KB
    const int tid  = threadIdx.x;
    const int lane = tid & 63;
    const int wave = tid >> 6;
    const int L     = blockIdx.x;
    const int btile = (L & 7) * 8 + ((L >> 3) & 7);   // XCD swizzle: x slice 3.2MB/XCD
    const int t     = L >> 6;
    const int b0    = btile * 128;
    const float* nb = noise + (size_t)t * ((size_t)NB * D_IN) + (size_t)b0 * D_IN;
    const float* xb = x + (size_t)b0 * D_IN;

    if (tid < 128) sB[tid * 50 + 49] = 0;              // k-pad ushort

    const int u = lane & 15;
    float4 nA, xA;
    nA = *reinterpret_cast<const float4*>(nb + (size_t)tid * 4);
    xA = *reinterpret_cast<const float4*>(xb + (size_t)tid * 4);
    #pragma unroll 2
    for (int p = 0; p < 98; ++p) {
        const float4 nC = nA, xC = xA;
        if (p < 97) {
            const size_t fo = (size_t)(p + 1) * 256 + tid;
            nA = *reinterpret_cast<const float4*>(nb + fo * 4);
            xA = *reinterpret_cast<const float4*>(xb + fo * 4);
        }
        const unsigned long long m0 = __ballot(nC.x < xC.x);
        const unsigned long long m1 = __ballot(nC.y < xC.y);
        const unsigned long long m2 = __ballot(nC.z < xC.z);
        const unsigned long long m3 = __ballot(nC.w < xC.w);
        if (lane < 16) {
            const uint32_t v = (uint32_t)((m0 >> (4 * u)) & 15ull)
                             | ((uint32_t)((m1 >> (4 * u)) & 15ull) << 4)
                             | ((uint32_t)((m2 >> (4 * u)) & 15ull) << 8)
                             | ((uint32_t)((m3 >> (4 * u)) & 15ull) << 12);
            const int g = p * 64 + wave * 16 + u;       // ushort-group index, 0..6271
            const uint32_t row = ((uint32_t)g * 42800u) >> 21;   // g/49 (exact for g<6272)
            const int colu = g - (int)row * 49;
            sB[row * 50 + colu] = (unsigned short)v;
        }
    }
    __syncthreads();
    const uint32_t* s32 = reinterpret_cast<const uint32_t*>(sB);
    #pragma unroll
    for (int p = 0; p < 13; ++p) {
        const int idx = p * 256 + tid;                  // (kt, bl)
        if (idx < 3200) {
            const int kt = idx >> 7, bl = idx & 127;
            bits[(size_t)(t * KT + kt) * NB + b0 + bl] = s32[bl * 25 + kt];
        }
    }
}

// ---------------- K2: H = spikes @ W1^T, bits input, no LDS/barriers ----------------
// Block: 256 thr = 4 waves as 2(M)x2(N); tile 128 rows x 128 h; grid 2048 = 32t x 64 btiles.
// A-frag element j of lane (lg = lane>>4): f = (lg&1)*8 + j within ushort u' = lg>>1;
// stored bit q = 4*(f&3) + (f>>2) + 16*u'. Dword d (j = 2d,2d+1):
//   qe = 2*(lg&1) + 16*(lg>>1) + 8*(d&1) + (d>>1); bits {qe, qe+4}.
__global__ __launch_bounds__(256) void bit_gemm(const uint32_t* __restrict__ bits,
                                                const unsigned short* __restrict__ wf,
                                                float* __restrict__ H) {
    const int tid   = threadIdx.x;
    const int lane  = tid & 63;
    const int wave  = tid >> 6;
    const int Mhalf = wave >> 1;
    const int Nhalf = wave & 1;
    const int bid   = blockIdx.x;
    const int btile = bid & 63;
    const int t     = bid >> 6;
    const int b0    = btile * 128;
    const int rowBase = b0 + Mhalf * 64 + (lane & 15);
    const int lg      = lane >> 4;
    const int qe0     = (lg & 1) * 2 + (lg >> 1) * 16;

    f32x4 acc[4][4];
    #pragma unroll
    for (int i = 0; i < 4; ++i)
        #pragma unroll
        for (int j = 0; j < 4; ++j) acc[i][j] = (f32x4){0.f, 0.f, 0.f, 0.f};

    #pragma unroll 2
    for (int kt = 0; kt < KT; ++kt) {
        const uint32_t* bptr = bits + (size_t)(t * KT + kt) * NB;
        uint32_t g[4];
        #pragma unroll
        for (int mt = 0; mt < 4; ++mt) g[mt] = bptr[rowBase + mt * 16];

        bf16x8 afr[4];
        #pragma unroll
        for (int mt = 0; mt < 4; ++mt) {
            union { uint32_t u[4]; bf16x8 v; } pk;
            #pragma unroll
            for (int d = 0; d < 4; ++d) {
                const int qe = qe0 + (d & 1) * 8 + (d >> 1);
                pk.u[d] = ((g[mt] >> qe) & 1u) * 0x3F80u
                        | ((g[mt] >> (qe + 4)) & 1u) * 0x3F800000u;
            }
            afr[mt] = pk.v;
        }
        #pragma unroll
        for (int nt = 0; nt < 4; ++nt) {
            const size_t fo = (size_t)(kt * 8 + Nhalf * 4 + nt) * 1024 + lane * 8;
            const bf16x8 bhi = *reinterpret_cast<const bf16x8*>(wf + fo);
            const bf16x8 blo = *reinterpret_cast<const bf16x8*>(wf + fo + 512);
            #pragma unroll
            for (int mt = 0; mt < 4; ++mt) {
                acc[mt][nt] = __builtin_amdgcn_mfma_f32_16x16x32_bf16(afr[mt], bhi, acc[mt][nt], 0, 0, 0);
                acc[mt][nt] = __builtin_amdgcn_mfma_f32_16x16x32_bf16(afr[mt], blo, acc[mt][nt], 0, 0, 0);
            }
        }
    }
    // C/D layout: col = lane&15, row = (lane>>4)*4 + reg.  H transposed [b][t][100].
    const int colBase   = Nhalf * 64 + (lane & 15);
    const int rowInTile = (lane >> 4) * 4;
    #pragma unroll
    for (int mt = 0; mt < 4; ++mt) {
        const int rowG = b0 + Mhalf * 64 + mt * 16 + rowInTile;
        #pragma unroll
        for (int nt = 0; nt < 4; ++nt) {
            const int col = colBase + nt * 16;
            if (col < DH) {
                #pragma unroll
                for (int r = 0; r < 4; ++r)
                    H[(size_t)(rowG + r) * (32 * DH) + t * DH + col] = acc[mt][nt][r];
            }
        }
    }
}

// ---------------- K3: IF scan over t + logits = cnt @ W2^T ----------------
// H transposed: row b = 3200 consecutive floats (t-major), block reads 25.6KB contiguous.
__global__ __launch_bounds__(256) void snn_scan(const float* __restrict__ H,
                                                const float* __restrict__ W2,
                                                float* __restrict__ out) {
    __shared__ float cbuf[2][104];
    __shared__ float w2s[1000];
    const int tid = threadIdx.x;
    const int r = tid >> 7, h = tid & 127;
    const size_t b = (size_t)blockIdx.x * 2 + r;
    for (int i = tid; i < 1000; i += 256) w2s[i] = W2[i];

    float cnt = 0.f;
    if (h < DH) {
        float hv[32];
        #pragma unroll
        for (int t = 0; t < 32; ++t) hv[t] = H[b * (32 * DH) + t * DH + h];
        float v = 0.f;
        #pragma unroll
        for (int t = 0; t < 32; ++t) {
            v += hv[t];
            float s = (v - 1.0f > 0.0f) ? 1.0f : 0.0f;  // exact reference semantics
            v -= s;
            cnt += s;
        }
    }
    if (h < DH) cbuf[r][h] = cnt;
    __syncthreads();
    if (tid < 20) {
        const int rr = tid / 10, o = tid % 10;
        float s = 0.f;
        for (int hh = 0; hh < DH; ++hh) s += cbuf[rr][hh] * w2s[o * DH + hh];
        out[((size_t)blockIdx.x * 2 + rr) * 10 + o] = s;
    }
}

extern "C" void kernel_launch(void* const* d_in, const int* in_sizes, int n_in,
                              void* d_out, int out_size, void* d_ws, size_t ws_size,
                              hipStream_t stream) {
    const float* x     = (const float*)d_in[0];   // [8192,784]
    const float* noise = (const float*)d_in[1];   // [32,8192,784]
    const float* W1    = (const float*)d_in[2];   // [100,784]
    const float* W2    = (const float*)d_in[3];   // [10,100]
    float* out = (float*)d_out;                   // [8192,10]

    unsigned short* wf = (unsigned short*)d_ws;                      // 400 KB W1 frags
    uint32_t* bits = (uint32_t*)((char*)d_ws + (1u << 20));          // 26.2 MB spike bits
    float* H = (float*)((char*)d_ws + (32u << 20));                  // 104.9 MB H buffer (transposed)

    prep_w1<<<50, 256, 0, stream>>>(W1, wf);
    pack_contig<<<2048, 256, 0, stream>>>(x, noise, bits);
    bit_gemm<<<2048, 256, 0, stream>>>(bits, wf, H);
    snn_scan<<<4096, 256, 0, stream>>>(H, W2, out);
}

// Round 7
// 328.683 us; speedup vs baseline: 1.1854x; 1.1081x over previous
//
#include <hip/hip_runtime.h>
#include <hip/hip_bf16.h>
#include <cstdint>

// SNN: Poisson encode (noise < x) -> [T=32] { h = sp@W1^T; v+=h; spike=(v>1); v-=spike; logits += spike@W2^T }
// B=8192, T=32, D_IN=784 (pad K to 800 = 25x32), D_H=100 (pad N to 128), D_OUT=10.
//
// v7: FUSED pack+gemm. Block (t, 128-row panel):
//   phase 1: stream noise+x contiguously (float4/lane), ballot-pack spike bits
//            into LDS [128][50] ushorts (12.8KB). No global bits traffic.
//   phase 2: one barrier, then bit-expand A-fragments from LDS + MFMA vs wf,
//            write H [b][t][100] (scan-friendly transposed layout).
//  K0 prep_w1, K2 snn_scan unchanged from v6.

typedef __attribute__((ext_vector_type(8))) short bf16x8;
typedef __attribute__((ext_vector_type(4))) float f32x4;

#define D_IN 784
#define NB 8192
#define KT 25   // K tiles of 32 (800 padded)
#define NTL 8   // N tiles of 16 (128 padded)
#define DH 100

// ---------------- K0: pack W1 into fragment-ready bf16 hi/lo ----------------
// Fragment f = (kt*8 + nt), stored as [f][hi(512 ushorts) | lo(512 ushorts)].
// B-slot(lane l, elem j): n = nt*16 + (l&15), i = kt*32 + (l>>4)*8 + j.
__global__ void prep_w1(const float* __restrict__ W1, unsigned short* __restrict__ wf) {
    int idx = blockIdx.x * 256 + threadIdx.x;           // 25*8*64 = 12800
    if (idx >= KT * NTL * 64) return;
    int l  = idx & 63;
    int nt = (idx >> 6) & 7;
    int kt = idx >> 9;
    int n  = nt * 16 + (l & 15);
    int i0 = kt * 32 + (l >> 4) * 8;
    size_t fbase = (size_t)(kt * 8 + nt) * 1024;
    #pragma unroll
    for (int j = 0; j < 8; ++j) {
        int i = i0 + j;
        float w = (n < DH && i < D_IN) ? W1[n * D_IN + i] : 0.f;
        uint32_t ub = __float_as_uint(w);
        uint32_t rh = ub + 0x7FFFu + ((ub >> 16) & 1u);
        unsigned short h = (unsigned short)(rh >> 16);
        float hf = __uint_as_float(((uint32_t)h) << 16);
        float resid = w - hf;
        uint32_t ul = __float_as_uint(resid);
        uint32_t rl = ul + 0x7FFFu + ((ul >> 16) & 1u);
        unsigned short lo = (unsigned short)(rl >> 16);
        wf[fbase + l * 8 + j]       = h;
        wf[fbase + 512 + l * 8 + j] = lo;
    }
}

// ---------------- K1: fused spike-pack + GEMM ----------------
// Pack (v6-verbatim): 98 passes x 256 thr x float4; ballot bits; lane<16 packs
// ushort-group g = p*64+wave*16+u -> sB[row][colu], row = g/49, colu = g%49.
// Stored bit q within ushort <-> float offset f: q = 4*(f&3)+(f>>2).
// Gemm (v6-verbatim except bits from LDS): A-frag dword d of lane-group lg:
//   qe = 2*(lg&1) + 16*(lg>>1) + 8*(d&1) + (d>>1); bits {qe, qe+4}.
__global__ __launch_bounds__(256) void snn_fused(const float* __restrict__ x,
                                                 const float* __restrict__ noise,
                                                 const unsigned short* __restrict__ wf,
                                                 float* __restrict__ H) {
    __shared__ __align__(4) unsigned short sB[128 * 50];   // 12.8KB spike bits
    const int tid  = threadIdx.x;
    const int lane = tid & 63;
    const int wave = tid >> 6;
    const int L     = blockIdx.x;
    const int btile = (L & 7) * 8 + ((L >> 3) & 7);   // XCD swizzle: x slice 3.2MB/XCD
    const int t     = L >> 6;
    const int b0    = btile * 128;
    const float* nb = noise + (size_t)t * ((size_t)NB * D_IN) + (size_t)b0 * D_IN;
    const float* xb = x + (size_t)b0 * D_IN;

    if (tid < 128) sB[tid * 50 + 49] = 0;              // k-pad ushort (bits 784..799)

    // ---- phase 1: pack ----
    {
        const int u = lane & 15;
        float4 nA, xA;
        nA = *reinterpret_cast<const float4*>(nb + (size_t)tid * 4);
        xA = *reinterpret_cast<const float4*>(xb + (size_t)tid * 4);
        #pragma unroll 2
        for (int p = 0; p < 98; ++p) {
            const float4 nC = nA, xC = xA;
            if (p < 97) {
                const size_t fo = (size_t)(p + 1) * 256 + tid;
                nA = *reinterpret_cast<const float4*>(nb + fo * 4);
                xA = *reinterpret_cast<const float4*>(xb + fo * 4);
            }
            const unsigned long long m0 = __ballot(nC.x < xC.x);
            const unsigned long long m1 = __ballot(nC.y < xC.y);
            const unsigned long long m2 = __ballot(nC.z < xC.z);
            const unsigned long long m3 = __ballot(nC.w < xC.w);
            if (lane < 16) {
                const uint32_t v = (uint32_t)((m0 >> (4 * u)) & 15ull)
                                 | ((uint32_t)((m1 >> (4 * u)) & 15ull) << 4)
                                 | ((uint32_t)((m2 >> (4 * u)) & 15ull) << 8)
                                 | ((uint32_t)((m3 >> (4 * u)) & 15ull) << 12);
                const int g = p * 64 + wave * 16 + u;       // 0..6271
                const uint32_t row = ((uint32_t)g * 42800u) >> 21;   // g/49 exact
                const int colu = g - (int)row * 49;
                sB[row * 50 + colu] = (unsigned short)v;
            }
        }
    }
    __syncthreads();

    // ---- phase 2: bit-GEMM ----
    const int Mhalf = wave >> 1;
    const int Nhalf = wave & 1;
    const int rowLoc = Mhalf * 64 + (lane & 15);
    const int lg     = lane >> 4;
    const int qe0    = (lg & 1) * 2 + (lg >> 1) * 16;
    const uint32_t* s32 = reinterpret_cast<const uint32_t*>(sB);

    f32x4 acc[4][4];
    #pragma unroll
    for (int i = 0; i < 4; ++i)
        #pragma unroll
        for (int j = 0; j < 4; ++j) acc[i][j] = (f32x4){0.f, 0.f, 0.f, 0.f};

    #pragma unroll 2
    for (int kt = 0; kt < KT; ++kt) {
        uint32_t g[4];
        #pragma unroll
        for (int mt = 0; mt < 4; ++mt) g[mt] = s32[(rowLoc + mt * 16) * 25 + kt];

        bf16x8 afr[4];
        #pragma unroll
        for (int mt = 0; mt < 4; ++mt) {
            union { uint32_t u[4]; bf16x8 v; } pk;
            #pragma unroll
            for (int d = 0; d < 4; ++d) {
                const int qe = qe0 + (d & 1) * 8 + (d >> 1);
                pk.u[d] = ((g[mt] >> qe) & 1u) * 0x3F80u
                        | ((g[mt] >> (qe + 4)) & 1u) * 0x3F800000u;
            }
            afr[mt] = pk.v;
        }
        #pragma unroll
        for (int nt = 0; nt < 4; ++nt) {
            const size_t fo = (size_t)(kt * 8 + Nhalf * 4 + nt) * 1024 + lane * 8;
            const bf16x8 bhi = *reinterpret_cast<const bf16x8*>(wf + fo);
            const bf16x8 blo = *reinterpret_cast<const bf16x8*>(wf + fo + 512);
            #pragma unroll
            for (int mt = 0; mt < 4; ++mt) {
                acc[mt][nt] = __builtin_amdgcn_mfma_f32_16x16x32_bf16(afr[mt], bhi, acc[mt][nt], 0, 0, 0);
                acc[mt][nt] = __builtin_amdgcn_mfma_f32_16x16x32_bf16(afr[mt], blo, acc[mt][nt], 0, 0, 0);
            }
        }
    }
    // C/D layout: col = lane&15, row = (lane>>4)*4 + reg.  H transposed [b][t][100].
    const int colBase   = Nhalf * 64 + (lane & 15);
    const int rowInTile = (lane >> 4) * 4;
    #pragma unroll
    for (int mt = 0; mt < 4; ++mt) {
        const int rowG = b0 + Mhalf * 64 + mt * 16 + rowInTile;
        #pragma unroll
        for (int nt = 0; nt < 4; ++nt) {
            const int col = colBase + nt * 16;
            if (col < DH) {
                #pragma unroll
                for (int r = 0; r < 4; ++r)
                    H[(size_t)(rowG + r) * (32 * DH) + t * DH + col] = acc[mt][nt][r];
            }
        }
    }
}

// ---------------- K2: IF scan over t + logits = cnt @ W2^T ----------------
// H transposed: row b = 3200 consecutive floats (t-major), block reads 25.6KB contiguous.
__global__ __launch_bounds__(256) void snn_scan(const float* __restrict__ H,
                                                const float* __restrict__ W2,
                                                float* __restrict__ out) {
    __shared__ float cbuf[2][104];
    __shared__ float w2s[1000];
    const int tid = threadIdx.x;
    const int r = tid >> 7, h = tid & 127;
    const size_t b = (size_t)blockIdx.x * 2 + r;
    for (int i = tid; i < 1000; i += 256) w2s[i] = W2[i];

    float cnt = 0.f;
    if (h < DH) {
        float hv[32];
        #pragma unroll
        for (int t = 0; t < 32; ++t) hv[t] = H[b * (32 * DH) + t * DH + h];
        float v = 0.f;
        #pragma unroll
        for (int t = 0; t < 32; ++t) {
            v += hv[t];
            float s = (v - 1.0f > 0.0f) ? 1.0f : 0.0f;  // exact reference semantics
            v -= s;
            cnt += s;
        }
    }
    if (h < DH) cbuf[r][h] = cnt;
    __syncthreads();
    if (tid < 20) {
        const int rr = tid / 10, o = tid % 10;
        float s = 0.f;
        for (int hh = 0; hh < DH; ++hh) s += cbuf[rr][hh] * w2s[o * DH + hh];
        out[((size_t)blockIdx.x * 2 + rr) * 10 + o] = s;
    }
}

extern "C" void kernel_launch(void* const* d_in, const int* in_sizes, int n_in,
                              void* d_out, int out_size, void* d_ws, size_t ws_size,
                              hipStream_t stream) {
    const float* x     = (const float*)d_in[0];   // [8192,784]
    const float* noise = (const float*)d_in[1];   // [32,8192,784]
    const float* W1    = (const float*)d_in[2];   // [100,784]
    const float* W2    = (const float*)d_in[3];   // [10,100]
    float* out = (float*)d_out;                   // [8192,10]

    unsigned short* wf = (unsigned short*)d_ws;                      // 400 KB W1 frags
    float* H = (float*)((char*)d_ws + (1u << 20));                   // 104.9 MB H (transposed)

    prep_w1<<<50, 256, 0, stream>>>(W1, wf);
    snn_fused<<<2048, 256, 0, stream>>>(x, noise, wf, H);
    snn_scan<<<4096, 256, 0, stream>>>(H, W2, out);
}